// Round 4
// baseline (744.154 us; speedup 1.0000x reference)
//
#include <hip/hip_runtime.h>
#include <hip/hip_bf16.h>
#include <math.h>

#define B_N 16384
#define D_K 256
#define JS 8
#define JRANGE (B_N / JS)          // 2048 j-rows per block
#define TJ 32                      // j-rows per LDS tile
#define NT (JRANGE / TJ)           // 64 tiles
#define TILE_BYTES (TJ * D_K * 2)  // 16 KB

typedef __bf16 bf16x8 __attribute__((ext_vector_type(8)));
typedef float f32x16 __attribute__((ext_vector_type(16)));

__device__ __forceinline__ unsigned short f2bf(float x) {
  unsigned u = __float_as_uint(x);
  unsigned r = (u + 0x7fffu + ((u >> 16) & 1u)) >> 16;
  return (unsigned short)r;
}

__device__ __forceinline__ float fexp2(float x) {
#if __has_builtin(__builtin_amdgcn_exp2f)
  return __builtin_amdgcn_exp2f(x);
#else
  return exp2f(x);
#endif
}

__device__ __forceinline__ void load_lds16(const void* g, void* l) {
  __builtin_amdgcn_global_load_lds(
      (const __attribute__((address_space(1))) unsigned int*)g,
      (__attribute__((address_space(3))) unsigned int*)l, 16, 0, 0);
}

// ---------------------------------------------------------------------------
// 1) fp32 -> bf16 (z_seal pre-scaled by scale*log2e) + diag fused.
//    Block = 4 rows (1024 floats); wave w <-> row 4*blockIdx+w.
// ---------------------------------------------------------------------------
__global__ void convert_diag_kernel(const float* __restrict__ A, const float* __restrict__ Bm,
                                    const float* __restrict__ lsp,
                                    unsigned short* __restrict__ Abf,
                                    unsigned short* __restrict__ Bbf,
                                    float* __restrict__ diag) {
  const float c = fminf(expf(lsp[0]), 100.0f) * 1.4426950408889634f;
  const int tid = threadIdx.x;
  const int idx = (blockIdx.x * 256 + tid) * 4;
  float4 a = *(const float4*)(A + idx);
  float4 b = *(const float4*)(Bm + idx);
  ushort4 ua, ub;
  ua.x = f2bf(a.x); ua.y = f2bf(a.y); ua.z = f2bf(a.z); ua.w = f2bf(a.w);
  ub.x = f2bf(b.x * c); ub.y = f2bf(b.y * c); ub.z = f2bf(b.z * c); ub.w = f2bf(b.w * c);
  *(ushort4*)(Abf + idx) = ua;
  *(ushort4*)(Bbf + idx) = ub;
  // diag (exact fp32, unscaled): row = idx/256 = blockIdx*4 + tid/64
  float d = a.x * b.x + a.y * b.y + a.z * b.z + a.w * b.w;
#pragma unroll
  for (int off = 32; off; off >>= 1) d += __shfl_xor(d, off);
  if ((tid & 63) == 0) diag[blockIdx.x * 4 + (tid >> 6)] = d;
}

// ---------------------------------------------------------------------------
// 2) Fused GEMM + online logsumexp (structure verified in R3).
//    upd: max3-friendly tree + 4 independent exp2 chains.
// ---------------------------------------------------------------------------
__device__ __forceinline__ void upd(float& m, float& s, const f32x16& a) {
  float x0 = fmaxf(fmaxf(a[0], a[1]), a[2]);
  float x1 = fmaxf(fmaxf(a[3], a[4]), a[5]);
  float x2 = fmaxf(fmaxf(a[6], a[7]), a[8]);
  float x3 = fmaxf(fmaxf(a[9], a[10]), a[11]);
  float x4 = fmaxf(fmaxf(a[12], a[13]), a[14]);
  float y0 = fmaxf(fmaxf(x0, x1), x2);
  float y1 = fmaxf(fmaxf(x3, x4), a[15]);
  float mn = fmaxf(m, fmaxf(y0, y1));
  s *= fexp2(m - mn);
  float p0 = fexp2(a[0] - mn), p1 = fexp2(a[1] - mn);
  float p2 = fexp2(a[2] - mn), p3 = fexp2(a[3] - mn);
  p0 += fexp2(a[4] - mn);  p1 += fexp2(a[5] - mn);
  p2 += fexp2(a[6] - mn);  p3 += fexp2(a[7] - mn);
  p0 += fexp2(a[8] - mn);  p1 += fexp2(a[9] - mn);
  p2 += fexp2(a[10] - mn); p3 += fexp2(a[11] - mn);
  p0 += fexp2(a[12] - mn); p1 += fexp2(a[13] - mn);
  p2 += fexp2(a[14] - mn); p3 += fexp2(a[15] - mn);
  s += (p0 + p1) + (p2 + p3);
  m = mn;
}

__global__ __launch_bounds__(256, 4) void lse_kernel(const unsigned short* __restrict__ Abf,
                                                     const unsigned short* __restrict__ Bbf,
                                                     float* __restrict__ pm,
                                                     float* __restrict__ ps) {
  __shared__ __align__(16) unsigned char lds[2][TILE_BYTES];
  const int bid = blockIdx.x;
  const int dir = bid >> 9;            // 0/1
  const int iblk = (bid >> 3) & 63;    // 64 i-blocks
  const int js = bid & 7;              // low bits -> same js pinned per XCD
  const unsigned short* X = dir ? Bbf : Abf;
  const unsigned short* Y = dir ? Abf : Bbf;
  const int i0 = iblk * 256;
  const int j0 = js * JRANGE;
  const int w = threadIdx.x >> 6;
  const int l = threadIdx.x & 63;
  const int lc = l & 31, lh = l >> 5;

  // X fragments: this wave's 64 rows x 256 k (128 VGPR)
  bf16x8 xf0[16], xf1[16];
  {
    const unsigned short* Xr0 = X + (size_t)(i0 + w * 64 + lc) * D_K + lh * 8;
#pragma unroll
    for (int kk = 0; kk < 16; ++kk) {
      xf0[kk] = *(const bf16x8*)(Xr0 + kk * 16);
      xf1[kk] = *(const bf16x8*)(Xr0 + 32 * D_K + kk * 16);
    }
  }

  float m0 = -INFINITY, s0 = 0.f, m1 = -INFINITY, s1 = 0.f;

  // Staging state: running per-lane swizzled source pointers (advance 1 tile
  // per STAGE call; STAGE calls happen in strict tile order 0,1,2,...).
  const unsigned short* srcs[4];
  unsigned dsts[4];
#pragma unroll
  for (int r = 0; r < 4; ++r) {
    const int row = w * 8 + 2 * r + lh;
    srcs[r] = Y + (size_t)(j0 + row) * D_K + ((lc ^ (row & 7)) << 3);
    dsts[r] = w * 4096 + r * 1024;
  }

#define STAGE(bufidx)                                  \
  {                                                    \
    _Pragma("unroll") for (int r = 0; r < 4; ++r) {    \
      load_lds16(srcs[r], &lds[bufidx][dsts[r]]);      \
      srcs[r] += TJ * D_K;                             \
    }                                                  \
  }

  // ds_read address: lc*512 + (((2kk+lh)^(lc&7))<<4)  ==  vb ^ (kk<<5)
  // (2kk+lh = 2kk^lh; shifts distribute over XOR; no carries since
  //  slot<<4 < 512). One v_xor per read.
  const unsigned vb = (unsigned)lc * 512 + ((unsigned)(lh ^ (lc & 7)) << 4);

#define CONSUME(bufidx)                                                          \
  {                                                                             \
    f32x16 acc0 = {};                                                           \
    f32x16 acc1 = {};                                                           \
    const unsigned char* lb = &lds[bufidx][0];                                  \
    __builtin_amdgcn_s_setprio(1);                                              \
    _Pragma("unroll") for (int kk = 0; kk < 16; ++kk) {                         \
      bf16x8 y = *(const bf16x8*)(lb + (vb ^ (unsigned)(kk << 5)));             \
      acc0 = __builtin_amdgcn_mfma_f32_32x32x16_bf16(y, xf0[kk], acc0, 0, 0, 0);\
      acc1 = __builtin_amdgcn_mfma_f32_32x32x16_bf16(y, xf1[kk], acc1, 0, 0, 0);\
    }                                                                           \
    __builtin_amdgcn_s_setprio(0);                                              \
    upd(m0, s0, acc0);                                                          \
    upd(m1, s1, acc1);                                                          \
  }

  STAGE(0);
  for (int t = 0; t < NT; t += 2) {
    __syncthreads();                   // buf0 ready (all waves' loads drained)
    if (t + 1 < NT) STAGE(1);          // prefetch next while computing
    CONSUME(0);
    __syncthreads();                   // buf1 ready; all done reading buf0
    if (t + 2 < NT) STAGE(0);
    CONSUME(1);
  }
#undef STAGE
#undef CONSUME

  // combine lane l with l^32 (same i, disjoint j_local subsets)
  {
    float mo = __shfl_xor(m0, 32), so = __shfl_xor(s0, 32);
    float mn = fmaxf(m0, mo);
    s0 = s0 * fexp2(m0 - mn) + so * fexp2(mo - mn); m0 = mn;
    mo = __shfl_xor(m1, 32); so = __shfl_xor(s1, 32);
    mn = fmaxf(m1, mo);
    s1 = s1 * fexp2(m1 - mn) + so * fexp2(mo - mn); m1 = mn;
  }

  // per-wave rows complete over this block's j-range: write partials
  if (lh == 0) {
    const int base = js * (2 * B_N) + dir * B_N + i0 + w * 64 + lc;
    pm[base] = m0;      ps[base] = s0;
    pm[base + 32] = m1; ps[base + 32] = s1;
  }
}

// ---------------------------------------------------------------------------
// 3) combine JS partials per (dir,i) -> lse (natural log)
// ---------------------------------------------------------------------------
__global__ void combine_kernel(const float* __restrict__ pm, const float* __restrict__ ps,
                               float* __restrict__ lse) {
  int id = blockIdx.x * 256 + threadIdx.x;  // dir*B_N + i
  float m = -INFINITY, s = 0.f;
#pragma unroll
  for (int p = 0; p < JS; ++p) {
    float mo = pm[p * (2 * B_N) + id], so = ps[p * (2 * B_N) + id];
    float mn = fmaxf(m, mo);
    s = s * fexp2(m - mn) + so * fexp2(mo - mn);
    m = mn;
  }
  lse[id] = 0.6931471805599453f * (m + log2f(s));
}

// ---------------------------------------------------------------------------
// 4) final: loss = mean( 0.5*(lse_r+lse_c) - scale*diag )
// ---------------------------------------------------------------------------
__global__ void final_kernel(const float* __restrict__ lse, const float* __restrict__ diag,
                             const float* __restrict__ lsp, float* __restrict__ out) {
  const float scale = fminf(expf(lsp[0]), 100.0f);
  float part = 0.f;
  for (int i = threadIdx.x; i < B_N; i += 1024)
    part += 0.5f * (lse[i] + lse[B_N + i]) - scale * diag[i];
  __shared__ float red[1024];
  red[threadIdx.x] = part;
  __syncthreads();
  for (int off = 512; off; off >>= 1) {
    if (threadIdx.x < off) red[threadIdx.x] += red[threadIdx.x + off];
    __syncthreads();
  }
  if (threadIdx.x == 0) {
    float loss = red[0] / (float)B_N;
    out[0] = loss;
    out[1] = loss;
  }
}

extern "C" void kernel_launch(void* const* d_in, const int* in_sizes, int n_in,
                              void* d_out, int out_size, void* d_ws, size_t ws_size,
                              hipStream_t stream) {
  const float* A  = (const float*)d_in[0];  // z_schema
  const float* Bm = (const float*)d_in[1];  // z_seal
  const float* ls = (const float*)d_in[2];  // logit_scale
  float* out = (float*)d_out;

  char* ws = (char*)d_ws;
  unsigned short* Abf = (unsigned short*)ws;                        // 8 MB
  unsigned short* Bbf = Abf + (size_t)B_N * D_K;                    // 8 MB
  float* diagp = (float*)(ws + 2ull * B_N * D_K * 2);               // 64 KB
  float* lsep  = diagp + B_N;                                       // 128 KB
  float* pm    = lsep + 2 * B_N;                                    // 1 MB
  float* ps    = pm + JS * 2 * B_N;                                 // 1 MB

  convert_diag_kernel<<<4096, 256, 0, stream>>>(A, Bm, ls, Abf, Bbf, diagp);
  lse_kernel<<<1024, 256, 0, stream>>>(Abf, Bbf, pm, ps);
  combine_kernel<<<128, 256, 0, stream>>>(pm, ps, lsep);
  final_kernel<<<1, 1024, 0, stream>>>(lsep, diagp, ls, out);
}

// Round 5
// 314.161 us; speedup vs baseline: 2.3687x; 2.3687x over previous
//
#include <hip/hip_runtime.h>
#include <hip/hip_bf16.h>
#include <math.h>

#define B_N 16384
#define D_K 256
#define JS 8
#define JRANGE (B_N / JS)          // 2048 j-rows per block
#define TJ 32                      // j-rows per LDS tile
#define NT (JRANGE / TJ)           // 64 tiles
#define TILE_BYTES (TJ * D_K * 2)  // 16 KB

typedef __bf16 bf16x8 __attribute__((ext_vector_type(8)));
typedef float f32x16 __attribute__((ext_vector_type(16)));

__device__ __forceinline__ unsigned short f2bf(float x) {
  unsigned u = __float_as_uint(x);
  unsigned r = (u + 0x7fffu + ((u >> 16) & 1u)) >> 16;
  return (unsigned short)r;
}

__device__ __forceinline__ float fexp2(float x) {
#if __has_builtin(__builtin_amdgcn_exp2f)
  return __builtin_amdgcn_exp2f(x);
#else
  return exp2f(x);
#endif
}

__device__ __forceinline__ void load_lds16(const void* g, void* l) {
  __builtin_amdgcn_global_load_lds(
      (const __attribute__((address_space(1))) unsigned int*)g,
      (__attribute__((address_space(3))) unsigned int*)l, 16, 0, 0);
}

// ---------------------------------------------------------------------------
// 1) fp32 -> bf16 (z_seal pre-scaled by scale*log2e) + diag fused.
// ---------------------------------------------------------------------------
__global__ void convert_diag_kernel(const float* __restrict__ A, const float* __restrict__ Bm,
                                    const float* __restrict__ lsp,
                                    unsigned short* __restrict__ Abf,
                                    unsigned short* __restrict__ Bbf,
                                    float* __restrict__ diag) {
  const float c = fminf(expf(lsp[0]), 100.0f) * 1.4426950408889634f;
  const int tid = threadIdx.x;
  const int idx = (blockIdx.x * 256 + tid) * 4;
  float4 a = *(const float4*)(A + idx);
  float4 b = *(const float4*)(Bm + idx);
  ushort4 ua, ub;
  ua.x = f2bf(a.x); ua.y = f2bf(a.y); ua.z = f2bf(a.z); ua.w = f2bf(a.w);
  ub.x = f2bf(b.x * c); ub.y = f2bf(b.y * c); ub.z = f2bf(b.z * c); ub.w = f2bf(b.w * c);
  *(ushort4*)(Abf + idx) = ua;
  *(ushort4*)(Bbf + idx) = ub;
  // diag (exact fp32, unscaled): row = blockIdx*4 + tid/64
  float d = a.x * b.x + a.y * b.y + a.z * b.z + a.w * b.w;
#pragma unroll
  for (int off = 32; off; off >>= 1) d += __shfl_xor(d, off);
  if ((tid & 63) == 0) diag[blockIdx.x * 4 + (tid >> 6)] = d;
}

// ---------------------------------------------------------------------------
// 2) Fused GEMM + online logsumexp.
//    CRITICAL: __launch_bounds__(256,2) — 2 waves/EU keeps the 128-VGPR
//    X-fragment array register-resident. (256,4) caps regs at 128 and the
//    compiler reloads X from global every tile: FETCH 72MB -> 2.45GB,
//    665 us (R4 regression). Do not raise.
// ---------------------------------------------------------------------------
__device__ __forceinline__ void upd(float& m, float& s, const f32x16& a) {
  float x0 = fmaxf(fmaxf(a[0], a[1]), a[2]);
  float x1 = fmaxf(fmaxf(a[3], a[4]), a[5]);
  float x2 = fmaxf(fmaxf(a[6], a[7]), a[8]);
  float x3 = fmaxf(fmaxf(a[9], a[10]), a[11]);
  float x4 = fmaxf(fmaxf(a[12], a[13]), a[14]);
  float y0 = fmaxf(fmaxf(x0, x1), x2);
  float y1 = fmaxf(fmaxf(x3, x4), a[15]);
  float mn = fmaxf(m, fmaxf(y0, y1));
  s *= fexp2(m - mn);
  float p0 = fexp2(a[0] - mn), p1 = fexp2(a[1] - mn);
  float p2 = fexp2(a[2] - mn), p3 = fexp2(a[3] - mn);
  p0 += fexp2(a[4] - mn);  p1 += fexp2(a[5] - mn);
  p2 += fexp2(a[6] - mn);  p3 += fexp2(a[7] - mn);
  p0 += fexp2(a[8] - mn);  p1 += fexp2(a[9] - mn);
  p2 += fexp2(a[10] - mn); p3 += fexp2(a[11] - mn);
  p0 += fexp2(a[12] - mn); p1 += fexp2(a[13] - mn);
  p2 += fexp2(a[14] - mn); p3 += fexp2(a[15] - mn);
  s += (p0 + p1) + (p2 + p3);
  m = mn;
}

__global__ __launch_bounds__(256, 2) void lse_kernel(const unsigned short* __restrict__ Abf,
                                                     const unsigned short* __restrict__ Bbf,
                                                     float* __restrict__ pm,
                                                     float* __restrict__ ps) {
  __shared__ __align__(16) unsigned char lds[2][TILE_BYTES];
  const int bid = blockIdx.x;
  const int dir = bid >> 9;            // 0/1
  const int iblk = (bid >> 3) & 63;    // 64 i-blocks
  const int js = bid & 7;              // low bits -> same js pinned per XCD
  const unsigned short* X = dir ? Bbf : Abf;
  const unsigned short* Y = dir ? Abf : Bbf;
  const int i0 = iblk * 256;
  const int j0 = js * JRANGE;
  const int w = threadIdx.x >> 6;
  const int l = threadIdx.x & 63;
  const int lc = l & 31, lh = l >> 5;

  // X fragments: this wave's 64 rows x 256 k (128 VGPR, register-resident)
  bf16x8 xf0[16], xf1[16];
  {
    const unsigned short* Xr0 = X + (size_t)(i0 + w * 64 + lc) * D_K + lh * 8;
#pragma unroll
    for (int kk = 0; kk < 16; ++kk) {
      xf0[kk] = *(const bf16x8*)(Xr0 + kk * 16);
      xf1[kk] = *(const bf16x8*)(Xr0 + 32 * D_K + kk * 16);
    }
  }

  float m0 = -INFINITY, s0 = 0.f, m1 = -INFINITY, s1 = 0.f;

  // Running per-lane swizzled source pointers (advance 1 tile per STAGE).
  const unsigned short* srcs[4];
  unsigned dsts[4];
#pragma unroll
  for (int r = 0; r < 4; ++r) {
    const int row = w * 8 + 2 * r + lh;
    srcs[r] = Y + (size_t)(j0 + row) * D_K + ((lc ^ (row & 7)) << 3);
    dsts[r] = w * 4096 + r * 1024;
  }

#define STAGE(bufidx)                                  \
  {                                                    \
    _Pragma("unroll") for (int r = 0; r < 4; ++r) {    \
      load_lds16(srcs[r], &lds[bufidx][dsts[r]]);      \
      srcs[r] += TJ * D_K;                             \
    }                                                  \
  }

  // ds_read address: lc*512 + (((2kk+lh)^(lc&7))<<4) == vb ^ (kk<<5)
  const unsigned vb = (unsigned)lc * 512 + ((unsigned)(lh ^ (lc & 7)) << 4);

#define CONSUME(bufidx)                                                          \
  {                                                                             \
    f32x16 acc0 = {};                                                           \
    f32x16 acc1 = {};                                                           \
    const unsigned char* lb = &lds[bufidx][0];                                  \
    __builtin_amdgcn_s_setprio(1);                                              \
    _Pragma("unroll") for (int kk = 0; kk < 16; ++kk) {                         \
      bf16x8 y = *(const bf16x8*)(lb + (vb ^ (unsigned)(kk << 5)));             \
      acc0 = __builtin_amdgcn_mfma_f32_32x32x16_bf16(y, xf0[kk], acc0, 0, 0, 0);\
      acc1 = __builtin_amdgcn_mfma_f32_32x32x16_bf16(y, xf1[kk], acc1, 0, 0, 0);\
    }                                                                           \
    __builtin_amdgcn_s_setprio(0);                                              \
    upd(m0, s0, acc0);                                                          \
    upd(m1, s1, acc1);                                                          \
  }

  STAGE(0);
  for (int t = 0; t < NT; t += 2) {
    __syncthreads();                   // buf0 ready (all waves' loads drained)
    if (t + 1 < NT) STAGE(1);          // prefetch next while computing
    CONSUME(0);
    __syncthreads();                   // buf1 ready; all done reading buf0
    if (t + 2 < NT) STAGE(0);
    CONSUME(1);
  }
#undef STAGE
#undef CONSUME

  // combine lane l with l^32 (same i, disjoint j_local subsets)
  {
    float mo = __shfl_xor(m0, 32), so = __shfl_xor(s0, 32);
    float mn = fmaxf(m0, mo);
    s0 = s0 * fexp2(m0 - mn) + so * fexp2(mo - mn); m0 = mn;
    mo = __shfl_xor(m1, 32); so = __shfl_xor(s1, 32);
    mn = fmaxf(m1, mo);
    s1 = s1 * fexp2(m1 - mn) + so * fexp2(mo - mn); m1 = mn;
  }

  // per-wave rows complete over this block's j-range: write partials
  if (lh == 0) {
    const int base = js * (2 * B_N) + dir * B_N + i0 + w * 64 + lc;
    pm[base] = m0;      ps[base] = s0;
    pm[base + 32] = m1; ps[base + 32] = s1;
  }
}

// ---------------------------------------------------------------------------
// 3) combine JS partials per (dir,i) -> lse (natural log)
// ---------------------------------------------------------------------------
__global__ void combine_kernel(const float* __restrict__ pm, const float* __restrict__ ps,
                               float* __restrict__ lse) {
  int id = blockIdx.x * 256 + threadIdx.x;  // dir*B_N + i
  float m = -INFINITY, s = 0.f;
#pragma unroll
  for (int p = 0; p < JS; ++p) {
    float mo = pm[p * (2 * B_N) + id], so = ps[p * (2 * B_N) + id];
    float mn = fmaxf(m, mo);
    s = s * fexp2(m - mn) + so * fexp2(mo - mn);
    m = mn;
  }
  lse[id] = 0.6931471805599453f * (m + log2f(s));
}

// ---------------------------------------------------------------------------
// 4) final: loss = mean( 0.5*(lse_r+lse_c) - scale*diag )
// ---------------------------------------------------------------------------
__global__ void final_kernel(const float* __restrict__ lse, const float* __restrict__ diag,
                             const float* __restrict__ lsp, float* __restrict__ out) {
  const float scale = fminf(expf(lsp[0]), 100.0f);
  float part = 0.f;
  for (int i = threadIdx.x; i < B_N; i += 1024)
    part += 0.5f * (lse[i] + lse[B_N + i]) - scale * diag[i];
  __shared__ float red[1024];
  red[threadIdx.x] = part;
  __syncthreads();
  for (int off = 512; off; off >>= 1) {
    if (threadIdx.x < off) red[threadIdx.x] += red[threadIdx.x + off];
    __syncthreads();
  }
  if (threadIdx.x == 0) {
    float loss = red[0] / (float)B_N;
    out[0] = loss;
    out[1] = loss;
  }
}

extern "C" void kernel_launch(void* const* d_in, const int* in_sizes, int n_in,
                              void* d_out, int out_size, void* d_ws, size_t ws_size,
                              hipStream_t stream) {
  const float* A  = (const float*)d_in[0];  // z_schema
  const float* Bm = (const float*)d_in[1];  // z_seal
  const float* ls = (const float*)d_in[2];  // logit_scale
  float* out = (float*)d_out;

  char* ws = (char*)d_ws;
  unsigned short* Abf = (unsigned short*)ws;                        // 8 MB
  unsigned short* Bbf = Abf + (size_t)B_N * D_K;                    // 8 MB
  float* diagp = (float*)(ws + 2ull * B_N * D_K * 2);               // 64 KB
  float* lsep  = diagp + B_N;                                       // 128 KB
  float* pm    = lsep + 2 * B_N;                                    // 1 MB
  float* ps    = pm + JS * 2 * B_N;                                 // 1 MB

  convert_diag_kernel<<<4096, 256, 0, stream>>>(A, Bm, ls, Abf, Bbf, diagp);
  lse_kernel<<<1024, 256, 0, stream>>>(Abf, Bbf, pm, ps);
  combine_kernel<<<128, 256, 0, stream>>>(pm, ps, lsep);
  final_kernel<<<1, 1024, 0, stream>>>(lsep, diagp, ls, out);
}